// Round 6
// baseline (261.489 us; speedup 1.0000x reference)
//
#include <hip/hip_runtime.h>
#include <hip/hip_bf16.h>
#include <math.h>

#define NB 1024
#define NC 100000
#define ND 512
#define SSCALE 64.0f
#define MMARGIN 0.5f

#define BM 256
#define BN 256
#define BK 64
#define NKS (ND / BK)                // 8 K-tiles
#define NRT (NB / BM)                // 4 row tiles
#define NCT ((NC + BN - 1) / BN)     // 391 col tiles
#define GRIDSZ (NRT * NCT)           // 1564

#define ABUF  32768                  // A: 2 x 32KB (256 rows x 128B)
#define BBASE 65536                  // B: 2 x 32KB (256 cls x 128B)
#define BBUF  32768

typedef __bf16 bf16x8 __attribute__((ext_vector_type(8)));
typedef float f32x4 __attribute__((ext_vector_type(4)));

__device__ __forceinline__ void gload_lds16(const void* g, void* l) {
    __builtin_amdgcn_global_load_lds(
        (const __attribute__((address_space(1))) unsigned int*)g,
        (__attribute__((address_space(3))) unsigned int*)l, 16, 0, 0);
}

// ---------------------------------------------------------------------------
// ws layout: [0,1MB) xnb bf16[NB][ND] ; then sums float[NB] ; tgt float[NB]
// ---------------------------------------------------------------------------

__global__ void prep_kernel(const float* __restrict__ x, __bf16* __restrict__ xnb) {
    const int row = blockIdx.x;
    const int tid = threadIdx.x;
    const float2 v = *reinterpret_cast<const float2*>(x + (size_t)row * ND + tid * 2);
    float ss = v.x * v.x + v.y * v.y;
#pragma unroll
    for (int m = 1; m < 64; m <<= 1) ss += __shfl_xor(ss, m);
    __shared__ float wsum[4];
    if ((tid & 63) == 0) wsum[tid >> 6] = ss;
    __syncthreads();
    const float tot = wsum[0] + wsum[1] + wsum[2] + wsum[3];
    const float inv = 1.0f / fmaxf(sqrtf(tot), 1e-12f);
    __bf16* dst = xnb + (size_t)row * ND + tid * 2;
    dst[0] = (__bf16)(v.x * inv);
    dst[1] = (__bf16)(v.y * inv);
}

__global__ void target_kernel(const __bf16* __restrict__ xnb, const float* __restrict__ Wg,
                              const int* __restrict__ labels, float* __restrict__ tgt) {
    const int wid  = threadIdx.x >> 6;
    const int lane = threadIdx.x & 63;
    const int row  = blockIdx.x * 4 + wid;
    const int lab  = labels[row];
    const int k    = lane * 8;
    const bf16x8 xv = *reinterpret_cast<const bf16x8*>(xnb + (size_t)row * ND + k);
    const float* wr = Wg + (size_t)lab * ND + k;
    const float4 w0 = *reinterpret_cast<const float4*>(wr);
    const float4 w1 = *reinterpret_cast<const float4*>(wr + 4);
    float s = (float)xv[0] * w0.x + (float)xv[1] * w0.y + (float)xv[2] * w0.z + (float)xv[3] * w0.w
            + (float)xv[4] * w1.x + (float)xv[5] * w1.y + (float)xv[6] * w1.z + (float)xv[7] * w1.w;
#pragma unroll
    for (int m = 1; m < 64; m <<= 1) s += __shfl_xor(s, m);
    if (lane == 0) tgt[row] = s;
}

// One phase: 8 swizzled ds_read_b128 -> issue slot -> barrier -> setprio(1)
// -> 16 MFMA (quadrant IH x KK) -> setprio(0). Caller emits the closing barrier.
#define DO_PHASE(IH, KK, ...)                                                     \
  {                                                                               \
    bf16x8 a[4], b[4];                                                            \
    const int ckk = ((KK) << 2) | lhi;                                            \
    _Pragma("unroll")                                                             \
    for (int i = 0; i < 4; ++i) {                                                 \
      const int r = wr * 128 + ((IH) * 4 + i) * 16 + l15;                         \
      a[i] = *reinterpret_cast<const bf16x8*>(                                    \
          lds + abase + r * 128 + ((ckk ^ (r & 7)) << 4));                        \
    }                                                                             \
    _Pragma("unroll")                                                             \
    for (int j = 0; j < 4; ++j) {                                                 \
      const int cls = wc * 64 + j * 16 + l15;                                     \
      b[j] = *reinterpret_cast<const bf16x8*>(                                    \
          lds + bbase + cls * 128 + ((ckk ^ (cls & 7)) << 4));                    \
    }                                                                             \
    __VA_ARGS__;                                                                  \
    asm volatile("s_barrier" ::: "memory");                                       \
    __builtin_amdgcn_s_setprio(1);                                                \
    _Pragma("unroll")                                                             \
    for (int i = 0; i < 4; ++i)                                                   \
      _Pragma("unroll")                                                           \
      for (int j = 0; j < 4; ++j)                                                 \
        acc[(IH) * 4 + i][j] = __builtin_amdgcn_mfma_f32_16x16x32_bf16(           \
            a[i], b[j], acc[(IH) * 4 + i][j], 0, 0, 0);                           \
    __builtin_amdgcn_s_setprio(0);                                                \
  }

// 256x256x64 GEMM, 8 waves (wave tile 128x64), 4-phase schedule per K-tile.
// A (bf16 xnb) via global_load_lds w16, pre-swizzled source, issued phase 0,
// drained (vmcnt 0) 4 phases later at tile end -> zero-cost. B (fp32 W) loads
// issued phases 0-1, cvt+swizzled ds_write phases 2-3 into the alternate
// buffer (T14). 128KB LDS, 1 block/CU. Fused exp + row-sum + atomic epilogue.
__global__ __launch_bounds__(512, 2) void gemm_exp_kernel(const __bf16* __restrict__ xnb,
                                                          const float* __restrict__ Wg,
                                                          float* __restrict__ sums) {
    __shared__ char lds[131072];
    const int tid  = threadIdx.x;
    const int wid  = tid >> 6;
    const int lane = tid & 63;
    const int l15  = lane & 15;
    const int lhi  = lane >> 4;
    const int wr   = wid >> 2;       // 0..1 : 128-row group
    const int wc   = wid & 3;        // 0..3 : 64-col group

    // bijective XCD swizzle (m204): q=GRIDSZ/8, rr=GRIDSZ%8
    const int xcd = blockIdx.x & 7, idx = blockIdx.x >> 3;
    const int q = GRIDSZ >> 3, rr = GRIDSZ & 7;
    const int wgid = (xcd < rr ? xcd * (q + 1) : rr * (q + 1) + (xcd - rr) * q) + idx;
    const int rt = wgid & 3;         // 4 consecutive logicals share ct -> W panel L2-resident
    const int ct = wgid >> 2;
    const int r0 = rt * BM;
    const int c0 = ct * BN;

    // ---- B: fp32 loads (half h: 128 cls), thread covers 64B of one cls row ----
    auto loadB = [&](int t, int h, float4 (&bw)[4]) {
        const int cls = h * 128 + (tid >> 2);
        const int ckb = tid & 3;
        if (c0 + cls < NC) {
            const float* s0 = Wg + (size_t)(c0 + cls) * ND + t * BK + ckb * 8;
            bw[0] = *reinterpret_cast<const float4*>(s0);
            bw[1] = *reinterpret_cast<const float4*>(s0 + 4);
            bw[2] = *reinterpret_cast<const float4*>(s0 + 32);
            bw[3] = *reinterpret_cast<const float4*>(s0 + 36);
        } else {
            bw[0] = make_float4(0.f, 0.f, 0.f, 0.f);
            bw[1] = bw[2] = bw[3] = bw[0];
        }
    };
    auto writeB = [&](int h, int buf, float4 (&bw)[4]) {
        const int cls = h * 128 + (tid >> 2);
        const int ckb = tid & 3;
        struct alignas(16) bf8s { __bf16 v[8]; };
        bf8s p0, p1;
        p0.v[0] = (__bf16)bw[0].x; p0.v[1] = (__bf16)bw[0].y; p0.v[2] = (__bf16)bw[0].z; p0.v[3] = (__bf16)bw[0].w;
        p0.v[4] = (__bf16)bw[1].x; p0.v[5] = (__bf16)bw[1].y; p0.v[6] = (__bf16)bw[1].z; p0.v[7] = (__bf16)bw[1].w;
        p1.v[0] = (__bf16)bw[2].x; p1.v[1] = (__bf16)bw[2].y; p1.v[2] = (__bf16)bw[2].z; p1.v[3] = (__bf16)bw[2].w;
        p1.v[4] = (__bf16)bw[3].x; p1.v[5] = (__bf16)bw[3].y; p1.v[6] = (__bf16)bw[3].z; p1.v[7] = (__bf16)bw[3].w;
        char* base = lds + BBASE + buf * BBUF + cls * 128;
        *reinterpret_cast<bf8s*>(base + ((ckb ^ (cls & 7)) << 4)) = p0;
        *reinterpret_cast<bf8s*>(base + (((ckb + 4) ^ (cls & 7)) << 4)) = p1;
    };
    // ---- A: 4 async gload_lds (linear dest, pre-swizzled source, rule 21) ----
    auto stageA = [&](int t, int buf) {
#pragma unroll
        for (int s = 0; s < 4; ++s) {
            const int row = s * 64 + wid * 8 + (lane >> 3);
            const int c   = lane & 7;
            const int sc  = c ^ (row & 7);
            const char* src = (const char*)xnb + (size_t)(r0 + row) * 1024 + t * 128 + sc * 16;
            gload_lds16(src, lds + buf * ABUF + s * 8192 + wid * 1024);
        }
    };

    f32x4 acc[8][4] = {};

    // ---- prologue: stage tile 0 into buffer 0 ----
    {
        float4 bw0[4], bw1[4];
        stageA(0, 0);
        loadB(0, 0, bw0);
        loadB(0, 1, bw1);
        writeB(0, 0, bw0);
        writeB(1, 0, bw1);
    }
    asm volatile("s_waitcnt vmcnt(0) lgkmcnt(0)\n\ts_barrier" ::: "memory");

#pragma unroll 1
    for (int kt = 0; kt < NKS; ++kt) {
        const int cur   = kt & 1;
        const int nxt   = cur ^ 1;
        const int abase = cur * ABUF;
        const int bbase = BBASE + cur * BBUF;
        const bool pf   = (kt + 1) < NKS;
        float4 bw0[4], bw1[4];

        DO_PHASE(0, 0, if (pf) { stageA(kt + 1, nxt); loadB(kt + 1, 0, bw0); })
        asm volatile("s_barrier" ::: "memory");
        DO_PHASE(1, 0, if (pf) { loadB(kt + 1, 1, bw1); })
        asm volatile("s_barrier" ::: "memory");
        DO_PHASE(0, 1, if (pf) { writeB(0, nxt, bw0); })
        asm volatile("s_barrier" ::: "memory");
        DO_PHASE(1, 1, if (pf) { writeB(1, nxt, bw1); })
        asm volatile("s_waitcnt vmcnt(0) lgkmcnt(0)\n\ts_barrier" ::: "memory");
    }

    // ---- epilogue: exp + row-sum over this wave's 64 cols + atomic ----
#pragma unroll
    for (int i = 0; i < 8; ++i) {
#pragma unroll
        for (int r = 0; r < 4; ++r) {
            float v = 0.f;
#pragma unroll
            for (int j = 0; j < 4; ++j) {
                const int c = c0 + wc * 64 + j * 16 + l15;
                v += (c < NC) ? __expf(SSCALE * acc[i][j][r]) : 0.f;
            }
            v += __shfl_xor(v, 1);
            v += __shfl_xor(v, 2);
            v += __shfl_xor(v, 4);
            v += __shfl_xor(v, 8);
            if (l15 == 0) {
                const int row = r0 + wr * 128 + i * 16 + lhi * 4 + r;
                atomicAdd(&sums[row], v);
            }
        }
    }
}

__global__ void finalize_kernel(const float* __restrict__ sums, const float* __restrict__ tgt,
                                float* __restrict__ out) {
    const int tid  = threadIdx.x;
    const int wid  = tid >> 6;
    const int lane = tid & 63;
    float t  = tgt[tid];
    const float se = sums[tid];
    t = fminf(fmaxf(t, -1.0f + 1e-7f), 1.0f - 1e-7f);
    const float numer = SSCALE * cosf(acosf(t) + MMARGIN);
    const float excl  = se - expf(SSCALE * t);
    float L = numer - logf(expf(numer) + excl);
#pragma unroll
    for (int m = 1; m < 64; m <<= 1) L += __shfl_xor(L, m);
    __shared__ float ws2[16];
    if (lane == 0) ws2[wid] = L;
    __syncthreads();
    if (tid == 0) {
        float tot = 0.f;
        for (int i = 0; i < 16; ++i) tot += ws2[i];
        out[0] = -(tot / (float)NB);
    }
}

extern "C" void kernel_launch(void* const* d_in, const int* in_sizes, int n_in,
                              void* d_out, int out_size, void* d_ws, size_t ws_size,
                              hipStream_t stream) {
    const float* x      = (const float*)d_in[0];
    const int*   labels = (const int*)d_in[1];
    const float* W      = (const float*)d_in[2];
    float* out = (float*)d_out;

    char* wsb = (char*)d_ws;
    __bf16* xnb  = (__bf16*)wsb;
    float*  sums = (float*)(wsb + (size_t)NB * ND * 2);
    float*  tgt  = sums + NB;

    hipMemsetAsync(sums, 0, NB * sizeof(float), stream);
    prep_kernel<<<NB, 256, 0, stream>>>(x, xnb);
    target_kernel<<<NB / 4, 256, 0, stream>>>(xnb, W, labels, tgt);
    gemm_exp_kernel<<<GRIDSZ, 512, 0, stream>>>(xnb, W, sums);
    finalize_kernel<<<1, 1024, 0, stream>>>(sums, tgt, out);
}